// Round 5
// baseline (379.592 us; speedup 1.0000x reference)
//
#include <hip/hip_runtime.h>
#include <hip/hip_bf16.h>
#include <hip/hip_fp16.h>
#include <math.h>

// GAT 2-layer forward, MI355X.
// Pipeline: [gemm1+att1 || range-partitioned bucket-build] -> [agg1+gemm2+att2] -> [agg2]
// Bucket build: 8 dst-ranges, each built by its own block group scanning the full
// edge stream (sequential reads, L3-served) so bucket writes stay L2-local.
// h1/h2 stored fp16; gathers are 16B/lane with shuffle-tree reduction.

constexpr int CAP  = 64;   // max in-degree capacity (Poisson(16)+1, P(>=63)~4e-19)
constexpr int DEGS = 4;    // deg counter stride (ints): spread atomic lines
constexpr int PAD  = 16;   // zero-padding for multi-edge gather loops
constexpr int NRANGE = 8;  // dst ranges (~= XCDs)
constexpr int PERIOD = 38; // 8 scatter + 30 gemm blocks per period

// ---------------- layer1 gemm+att fused with range-partitioned bucketing ----------------
__global__ __launch_bounds__(256)
void k_l1_fused(const float* __restrict__ x, const float* __restrict__ W,
                const float* __restrict__ al, const float* __restrict__ ar,
                __half* __restrict__ hbuf, float* __restrict__ el, float* __restrict__ er,
                int nnodes,
                const int* __restrict__ src, const int* __restrict__ dst,
                int* __restrict__ deg, int* __restrict__ bucket, int E, int CHUNK)
{
    constexpr int IN = 128, H = 2, D = 32, OUT = H * D, NPB = 256 / OUT, IN4 = IN / 4;

    const int p = blockIdx.x / PERIOD, slot = blockIdx.x % PERIOD;
    if (slot < NRANGE) {
        // ---- scatter role: scan edge chunk p, keep dst in range (bid&7) ----
        const int r  = blockIdx.x & 7;          // == default XCD of this block
        const int lo = (int)((long)r * nnodes / NRANGE);
        const int hi = (int)((long)(r + 1) * nnodes / NRANGE);
        const int e0 = p * CHUNK;
        const int e1 = min(e0 + CHUNK, E);
        for (int e = e0 + (int)threadIdx.x; e < e1; e += 256) {
            const int d = dst[e];
            const int s = src[e];
            if (d >= lo && d < hi) {
                const int pos = atomicAdd(&deg[d * DEGS], 1);
                if (pos < CAP) bucket[(long)d * CAP + pos] = s;
            }
        }
        return;
    }
    // ---- gemm role ----
    const int gi    = p * (PERIOD - NRANGE) + (slot - NRANGE);
    const int node0 = gi * NPB;
    if (node0 >= nnodes) return;                 // block-uniform exit
    __shared__ float xs[NPB * IN];
    const int tid = threadIdx.x;

    for (int idx = tid; idx < NPB * IN4; idx += 256) {
        const int node = node0 + idx / IN4;
        float4 v = make_float4(0.f, 0.f, 0.f, 0.f);
        if (node < nnodes) v = ((const float4*)x)[(long)node * IN4 + (idx % IN4)];
        ((float4*)xs)[idx] = v;
    }
    __syncthreads();

    const int nl = tid / OUT, j = tid % OUT;
    const int node = node0 + nl;
    if (node >= nnodes) return;

    float a0 = 0.f, a1 = 0.f, a2 = 0.f, a3 = 0.f;
    #pragma unroll
    for (int k = 0; k < IN; k += 4) {
        a0 = fmaf(xs[nl*IN + k    ], W[(k    )*OUT + j], a0);
        a1 = fmaf(xs[nl*IN + k + 1], W[(k + 1)*OUT + j], a1);
        a2 = fmaf(xs[nl*IN + k + 2], W[(k + 2)*OUT + j], a2);
        a3 = fmaf(xs[nl*IN + k + 3], W[(k + 3)*OUT + j], a3);
    }
    const float acc = (a0 + a1) + (a2 + a3);
    hbuf[(long)node * OUT + j] = __float2half(acc);

    const int head = j / D, d = j % D;           // lane == j here (OUT==64)
    float ep = acc * al[head*D + d];
    float rp = acc * ar[head*D + d];
    #pragma unroll
    for (int off = 16; off; off >>= 1) {          // reduce within 32-lane half
        ep += __shfl_xor(ep, off, 64);
        rp += __shfl_xor(rp, off, 64);
    }
    if (d == 0) { el[(long)node*H + head] = ep; er[(long)node*H + head] = rp; }
}

// ------------- agg layer1 + gemm2 + att2, one wave per node -------------
__global__ __launch_bounds__(256)
void k_agg1_gemm2(const __half* __restrict__ hbuf, const float* __restrict__ el,
                  const float* __restrict__ er, const int* __restrict__ deg,
                  const int* __restrict__ bucket, const float* __restrict__ b1,
                  const float* __restrict__ W2, const float* __restrict__ al2,
                  const float* __restrict__ ar2,
                  __half* __restrict__ h2, float* __restrict__ el2, float* __restrict__ er2,
                  int nnodes)
{
    constexpr int H = 2, OUT = 64, OUT2 = 32;
    const int w = threadIdx.x >> 6, lane = threadIdx.x & 63;
    const int n = blockIdx.x * 4 + w;
    __shared__ int   sbuf[4][CAP + PAD];
    __shared__ float wbuf[4][H][CAP + PAD];
    __shared__ float orow[4][OUT];
    if (n >= nnodes) return;                       // wave-level exit; no barriers used

    const int dn = min(deg[n * DEGS], CAP);
    for (int i = lane; i < dn; i += 64) sbuf[w][i] = bucket[(long)n * CAP + i];
    if (lane < PAD) {                               // zero-pad for branch-free gather
        sbuf[w][dn + lane]    = 0;
        wbuf[w][0][dn + lane] = 0.f;
        wbuf[w][1][dn + lane] = 0.f;
    }

    // per-head softmax: 32 lanes per head
    const int h = lane >> 5, li = lane & 31;
    const float ern = er[(long)n*H + h];
    float m = -INFINITY;
    for (int i = li; i < dn; i += 32) {
        float e = el[(long)sbuf[w][i]*H + h] + ern;
        e = (e > 0.f) ? e : 0.2f * e;              // leaky_relu 0.2
        wbuf[w][h][i] = e;
        m = fmaxf(m, e);
    }
    #pragma unroll
    for (int off = 16; off; off >>= 1) m = fmaxf(m, __shfl_xor(m, off, 64));
    float s = 0.f;
    for (int i = li; i < dn; i += 32) {
        float v = __expf(wbuf[w][h][i] - m);
        wbuf[w][h][i] = v;
        s += v;
    }
    #pragma unroll
    for (int off = 16; off; off >>= 1) s += __shfl_xor(s, off, 64);
    const float invh = (s > 0.f) ? 1.f / s : 0.f;
    const float inv0 = __shfl(invh, 0, 64);
    const float inv1 = __shfl(invh, 32, 64);

    // gather: 8 lanes/row (16B half8 each), 16 edge slots/iter (2x unroll)
    const int q  = lane >> 3;                      // edge slot 0..7
    const int c8 = lane & 7;                       // channel octet c8*8..c8*8+7
    const int hh = c8 >> 2;                        // head of this octet
    const float invC = hh ? inv1 : inv0;
    float acc[8] = {0.f,0.f,0.f,0.f,0.f,0.f,0.f,0.f};
    for (int i = 0; i < dn; i += 16) {
        const int   sA = sbuf[w][i + q],         sB = sbuf[w][i + 8 + q];
        const float wA = wbuf[w][hh][i + q],     wB = wbuf[w][hh][i + 8 + q];
        union { float4 f4; __half2 h2v[4]; } uA, uB;
        uA.f4 = *(const float4*)(hbuf + (long)sA*OUT + c8*8);
        uB.f4 = *(const float4*)(hbuf + (long)sB*OUT + c8*8);
        #pragma unroll
        for (int j = 0; j < 4; j++) {
            const float2 xa = __half22float2(uA.h2v[j]);
            const float2 xb = __half22float2(uB.h2v[j]);
            acc[2*j]   = fmaf(xa.x, wA, acc[2*j]);
            acc[2*j+1] = fmaf(xa.y, wA, acc[2*j+1]);
            acc[2*j]   = fmaf(xb.x, wB, acc[2*j]);
            acc[2*j+1] = fmaf(xb.y, wB, acc[2*j+1]);
        }
    }
    #pragma unroll
    for (int j = 0; j < 8; j++) {                  // reduce over the 8 edge slots
        acc[j] += __shfl_xor(acc[j], 8, 64);
        acc[j] += __shfl_xor(acc[j], 16, 64);
        acc[j] += __shfl_xor(acc[j], 32, 64);
    }
    if (q == 0) {
        #pragma unroll
        for (int j = 0; j < 8; j++)
            orow[w][c8*8 + j] = fmaxf(acc[j] * invC + b1[c8*8 + j], 0.f);
    }

    // gemm2 (64->32) with 2-way k-split + att2 dots, all in-wave
    const int p = lane >> 5, j2 = lane & 31;
    float g = 0.f;
    #pragma unroll
    for (int k = 0; k < 32; k++)
        g = fmaf(orow[w][p*32 + k], W2[(p*32 + k)*OUT2 + j2], g);
    g += __shfl_xor(g, 32, 64);                    // both halves now hold h2[n][j2]

    float ev = g * al2[j2], rv = g * ar2[j2];
    #pragma unroll
    for (int off = 16; off; off >>= 1) { ev += __shfl_xor(ev, off, 64); rv += __shfl_xor(rv, off, 64); }
    if (lane < 32) h2[(long)n*OUT2 + j2] = __float2half(g);
    if (lane == 0) { el2[n] = ev; er2[n] = rv; }
}

// ---------------- agg layer2 (final output) ----------------
__global__ __launch_bounds__(256)
void k_agg2(const __half* __restrict__ h2, const float* __restrict__ el2,
            const float* __restrict__ er2, const int* __restrict__ deg,
            const int* __restrict__ bucket, const float* __restrict__ b2,
            float* __restrict__ out, int nnodes)
{
    constexpr int OUT2 = 32;
    const int w = threadIdx.x >> 6, lane = threadIdx.x & 63;
    const int n = blockIdx.x * 4 + w;
    __shared__ int   sbuf[4][CAP + PAD];
    __shared__ float wbuf[4][CAP + PAD];
    if (n >= nnodes) return;

    const int dn = min(deg[n * DEGS], CAP);
    for (int i = lane; i < dn; i += 64) sbuf[w][i] = bucket[(long)n * CAP + i];
    if (lane < PAD) {
        sbuf[w][dn + lane] = 0;
        wbuf[w][dn + lane] = 0.f;
    }

    const float ern = er2[n];
    float m = -INFINITY;
    for (int i = lane; i < dn; i += 64) {
        float e = el2[sbuf[w][i]] + ern;
        e = (e > 0.f) ? e : 0.2f * e;
        wbuf[w][i] = e;
        m = fmaxf(m, e);
    }
    #pragma unroll
    for (int off = 32; off; off >>= 1) m = fmaxf(m, __shfl_xor(m, off, 64));
    float s = 0.f;
    for (int i = lane; i < dn; i += 64) {
        float v = __expf(wbuf[w][i] - m);
        wbuf[w][i] = v;
        s += v;
    }
    #pragma unroll
    for (int off = 32; off; off >>= 1) s += __shfl_xor(s, off, 64);
    const float inv = (s > 0.f) ? 1.f / s : 0.f;

    // gather: 4 lanes/row (16B half8 each), 16 edge slots/iter
    const int q  = lane >> 2;                      // edge slot 0..15
    const int c8 = lane & 3;                       // channel octet c8*8..c8*8+7
    float acc[8] = {0.f,0.f,0.f,0.f,0.f,0.f,0.f,0.f};
    for (int i = 0; i < dn; i += 16) {
        const int   sA = sbuf[w][i + q];
        const float wA = wbuf[w][i + q];
        union { float4 f4; __half2 h2v[4]; } uA;
        uA.f4 = *(const float4*)(h2 + (long)sA*OUT2 + c8*8);
        #pragma unroll
        for (int j = 0; j < 4; j++) {
            const float2 xa = __half22float2(uA.h2v[j]);
            acc[2*j]   = fmaf(xa.x, wA, acc[2*j]);
            acc[2*j+1] = fmaf(xa.y, wA, acc[2*j+1]);
        }
    }
    #pragma unroll
    for (int j = 0; j < 8; j++) {                  // reduce over the 16 edge slots
        acc[j] += __shfl_xor(acc[j], 4, 64);
        acc[j] += __shfl_xor(acc[j], 8, 64);
        acc[j] += __shfl_xor(acc[j], 16, 64);
        acc[j] += __shfl_xor(acc[j], 32, 64);
    }
    if (q == 0) {                                  // lanes 0..3 write 8 ch each
        float r[8];
        #pragma unroll
        for (int j = 0; j < 8; j++)
            r[j] = fmaxf(acc[j] * inv + b2[c8*8 + j], 0.f);
        float4* po = (float4*)(out + (long)n*OUT2 + c8*8);
        po[0] = make_float4(r[0], r[1], r[2], r[3]);
        po[1] = make_float4(r[4], r[5], r[6], r[7]);
    }
}

extern "C" void kernel_launch(void* const* d_in, const int* in_sizes, int n_in,
                              void* d_out, int out_size, void* d_ws, size_t ws_size,
                              hipStream_t stream)
{
    const float* feat = (const float*)d_in[0];
    const float* W1   = (const float*)d_in[1];
    const float* al1  = (const float*)d_in[2];
    const float* ar1  = (const float*)d_in[3];
    const float* b1   = (const float*)d_in[4];
    const float* W2   = (const float*)d_in[5];
    const float* al2  = (const float*)d_in[6];
    const float* ar2  = (const float*)d_in[7];
    const float* b2   = (const float*)d_in[8];
    const int*   src  = (const int*)d_in[9];
    const int*   dst  = (const int*)d_in[10];

    const int N = in_sizes[0] / 128;   // 100000
    const int E = in_sizes[9];         // 1.7M

    char* ws = (char*)d_ws;
    size_t off = 0;
    auto alloc = [&](size_t bytes) -> void* {
        void* p = ws + off;
        off += (bytes + 255) & ~size_t(255);
        return p;
    };
    int*    deg    = (int*)   alloc((size_t)N * DEGS * 4);
    int*    bucket = (int*)   alloc((size_t)N * CAP * 4);
    __half* h1     = (__half*)alloc((size_t)N * 64 * 2);
    float*  el1    = (float*) alloc((size_t)N * 2 * 4);
    float*  er1    = (float*) alloc((size_t)N * 2 * 4);
    __half* h2     = (__half*)alloc((size_t)N * 32 * 2);
    float*  el2    = (float*) alloc((size_t)N * 4);
    float*  er2    = (float*) alloc((size_t)N * 4);

    hipMemsetAsync(deg, 0, (size_t)N * DEGS * 4, stream);

    // grid layout: NP periods of [8 scatter + 30 gemm] blocks
    const int Ngemm = (N + 3) / 4;                       // gemm blocks (4 nodes each)
    const int NP    = (Ngemm + PERIOD - NRANGE - 1) / (PERIOD - NRANGE);
    const int CHUNK = (E + NP - 1) / NP;                 // edges per scatter block
    const int TOT   = NP * PERIOD;

    k_l1_fused<<<TOT, 256, 0, stream>>>(feat, W1, al1, ar1, h1, el1, er1, N,
                                        src, dst, deg, bucket, E, CHUNK);
    k_agg1_gemm2<<<(N + 3) / 4, 256, 0, stream>>>(h1, el1, er1, deg, bucket, b1,
                                                  W2, al2, ar2, h2, el2, er2, N);
    k_agg2<<<(N + 3) / 4, 256, 0, stream>>>(h2, el2, er2, deg, bucket, b2,
                                            (float*)d_out, N);
}

// Round 6
// 309.303 us; speedup vs baseline: 1.2273x; 1.2273x over previous
//
#include <hip/hip_runtime.h>
#include <hip/hip_bf16.h>
#include <hip/hip_fp16.h>
#include <math.h>

// GAT 2-layer forward, MI355X.
// [k_prew] [k_bin -> k_scatter]  (binned two-phase bucket build, LDS-resident windows)
// [k_gemm1 MFMA fp16] [k_att1 fp32 logits]  -> [agg1+gemm2+att2] -> [agg2]

constexpr int CAP  = 64;    // max in-degree capacity
constexpr int PAD  = 16;    // zero-padding for gather loops
constexpr int MAXB = 256;   // max bins (N <= 131072)
constexpr int TILE = 2048;  // edges per k_bin block
constexpr int BCAP = 12288; // records per bin capacity (~38 sigma margin)

typedef _Float16 f16x8 __attribute__((ext_vector_type(8)));
typedef float    f32x4 __attribute__((ext_vector_type(4)));

// ---- phase 1: bin edges into 512-node dst ranges, packed records ----
__global__ __launch_bounds__(256)
void k_bin(const int* __restrict__ src, const int* __restrict__ dst,
           int* __restrict__ gcur, unsigned* __restrict__ binbuf, int E, int nbins)
{
    __shared__ int cnt[MAXB];
    __shared__ int base[MAXB];
    const int t = threadIdx.x;
    for (int b = t; b < nbins; b += 256) cnt[b] = 0;
    __syncthreads();
    const int e0 = blockIdx.x * TILE;
    int lo[8]; unsigned rec[8]; int bn[8];
    #pragma unroll
    for (int u = 0; u < 8; u++) {
        const int e = e0 + u * 256 + t;
        if (e < E) {
            const int d = dst[e], s = src[e];
            bn[u]  = d >> 9;
            rec[u] = ((unsigned)s << 9) | (unsigned)(d & 511);
            lo[u]  = atomicAdd(&cnt[bn[u]], 1);
        } else bn[u] = -1;
    }
    __syncthreads();
    for (int b = t; b < nbins; b += 256) {
        const int c = cnt[b];
        base[b] = c ? atomicAdd(&gcur[b], c) : 0;
    }
    __syncthreads();
    #pragma unroll
    for (int u = 0; u < 8; u++) if (bn[u] >= 0) {
        const int p = base[bn[u]] + lo[u];
        if (p < BCAP) binbuf[(long)bn[u] * BCAP + p] = rec[u];
    }
}

// ---- phase 2: per-bin LDS bucket window, dense write-out ----
__global__ __launch_bounds__(256)
void k_scatter(const unsigned* __restrict__ binbuf, const int* __restrict__ gcur,
               int* __restrict__ deg, int* __restrict__ bucket, int nnodes)
{
    extern __shared__ int lds[];          // ldeg[512] + lbuck[512*CAP]
    int* ldeg  = lds;
    int* lbuck = lds + 512;
    const int t = threadIdx.x, b = blockIdx.x;
    const int nb0 = b << 9;
    for (int i = t; i < 512; i += 256) ldeg[i] = 0;
    __syncthreads();
    const int cnt = min(gcur[b], BCAP);
    const unsigned* recs = binbuf + (long)b * BCAP;
    for (int i = t; i < cnt; i += 256) {
        const unsigned r = recs[i];
        const int nl  = (int)(r & 511u);
        const int pos = atomicAdd(&ldeg[nl], 1);
        if (pos < CAP) lbuck[nl * CAP + pos] = (int)(r >> 9);
    }
    __syncthreads();
    const int nv = min(512, nnodes - nb0);
    for (int i = t; i < nv; i += 256) deg[nb0 + i] = ldeg[i];
    const int tot4 = nv * (CAP / 4);
    int4* gb = (int4*)(bucket + (long)nb0 * CAP);
    const int4* lb = (const int4*)lbuck;
    for (int i = t; i < tot4; i += 256) gb[i] = lb[i];
}

// ---- v = [W·al per head, W·ar per head]: 4 vectors of 128 (fp32 logits) ----
__global__ void k_prew(const float* __restrict__ W, const float* __restrict__ al,
                       const float* __restrict__ ar, float* __restrict__ v)
{
    for (int i = threadIdx.x; i < 512; i += 256) {
        const int vec = i >> 7, k = i & 127;
        const int h = vec & 1;
        const float* a = (vec >> 1) ? ar : al;
        float s = 0.f;
        #pragma unroll
        for (int d = 0; d < 32; d++) s += W[k * 64 + h * 32 + d] * a[h * 32 + d];
        v[vec * 128 + k] = s;
    }
}

// ---- layer-1 GEMM via MFMA 16x16x32 f16; h1 out fp16 ----
__global__ __launch_bounds__(256)
void k_gemm1(const float* __restrict__ x, const float* __restrict__ W,
             __half* __restrict__ h1, int nnodes)
{
    __shared__ _Float16 xs[64 * 128];   // XOR-swizzled rows ((row&7)<<4 on byte addr)
    __shared__ _Float16 Wh[128 * 64];
    const int tid = threadIdx.x;
    const int node0 = blockIdx.x * 64;

    for (int c = tid; c < 1024; c += 256) {          // x: 64 rows x 16 chunks of 8
        const int row = c >> 4, k8 = c & 15;
        const int n = node0 + row;
        float4 v0 = make_float4(0,0,0,0), v1 = v0;
        if (n < nnodes) {
            v0 = ((const float4*)x)[(long)n * 32 + k8 * 2];
            v1 = ((const float4*)x)[(long)n * 32 + k8 * 2 + 1];
        }
        f16x8 h;
        h[0]=v0.x; h[1]=v0.y; h[2]=v0.z; h[3]=v0.w;
        h[4]=v1.x; h[5]=v1.y; h[6]=v1.z; h[7]=v1.w;
        const int off = (row * 256 + k8 * 16) ^ ((row & 7) << 4);
        *(f16x8*)((char*)xs + off) = h;
    }
    for (int c = tid; c < 1024; c += 256) {          // W: 128 rows x 8 chunks of 8
        const int k = c >> 3, j8 = (c & 7) * 8;
        float4 v0 = ((const float4*)W)[(k * 64 + j8) >> 2];
        float4 v1 = ((const float4*)W)[((k * 64 + j8) >> 2) + 1];
        f16x8 h;
        h[0]=v0.x; h[1]=v0.y; h[2]=v0.z; h[3]=v0.w;
        h[4]=v1.x; h[5]=v1.y; h[6]=v1.z; h[7]=v1.w;
        *(f16x8*)(Wh + k * 64 + j8) = h;
    }
    __syncthreads();

    const int wv = tid >> 6, l = tid & 63;
    const int col = wv * 16 + (l & 15);
    const int g = l >> 4;
    f16x8 bfr[4];
    #pragma unroll
    for (int t = 0; t < 4; t++)
        #pragma unroll
        for (int e = 0; e < 8; e++)
            bfr[t][e] = Wh[(t * 32 + g * 8 + e) * 64 + col];

    #pragma unroll
    for (int nt = 0; nt < 4; nt++) {
        f32x4 acc = {0.f, 0.f, 0.f, 0.f};
        const int row = nt * 16 + (l & 15);
        #pragma unroll
        for (int t = 0; t < 4; t++) {
            const int off = (row * 256 + (t * 32 + g * 8) * 2) ^ ((row & 7) << 4);
            f16x8 af = *(const f16x8*)((const char*)xs + off);
            acc = __builtin_amdgcn_mfma_f32_16x16x32_f16(af, bfr[t], acc, 0, 0, 0);
        }
        #pragma unroll
        for (int r = 0; r < 4; r++) {
            const int n = node0 + nt * 16 + g * 4 + r;
            if (n < nnodes) h1[(long)n * 64 + col] = __float2half((float)acc[r]);
        }
    }
}

// ---- el/er layer 1 from fp32 x and precomputed v (exact logits) ----
__global__ __launch_bounds__(256)
void k_att1(const float* __restrict__ x, const float* __restrict__ v,
            float* __restrict__ el, float* __restrict__ er, int nnodes)
{
    __shared__ float vs[512];
    for (int i = threadIdx.x; i < 512; i += 256) vs[i] = v[i];
    __syncthreads();
    const int gt = blockIdx.x * 256 + threadIdx.x;
    const int n = gt >> 4, li = gt & 15;
    if (n >= nnodes) return;
    const float4 xa = ((const float4*)x)[(long)n * 32 + li * 2];
    const float4 xb = ((const float4*)x)[(long)n * 32 + li * 2 + 1];
    float d0[4];
    #pragma unroll
    for (int vv = 0; vv < 4; vv++) {
        const float* vp = vs + vv * 128 + li * 8;
        d0[vv] = xa.x*vp[0] + xa.y*vp[1] + xa.z*vp[2] + xa.w*vp[3]
               + xb.x*vp[4] + xb.y*vp[5] + xb.z*vp[6] + xb.w*vp[7];
    }
    #pragma unroll
    for (int vv = 0; vv < 4; vv++) {
        d0[vv] += __shfl_xor(d0[vv], 1, 64);
        d0[vv] += __shfl_xor(d0[vv], 2, 64);
        d0[vv] += __shfl_xor(d0[vv], 4, 64);
        d0[vv] += __shfl_xor(d0[vv], 8, 64);
    }
    if (li == 0) {
        el[n * 2] = d0[0]; el[n * 2 + 1] = d0[1];
        er[n * 2] = d0[2]; er[n * 2 + 1] = d0[3];
    }
}

// ------------- agg layer1 + gemm2 + att2, one wave per node -------------
__global__ __launch_bounds__(256)
void k_agg1_gemm2(const __half* __restrict__ hbuf, const float* __restrict__ el,
                  const float* __restrict__ er, const int* __restrict__ deg,
                  const int* __restrict__ bucket, const float* __restrict__ b1,
                  const float* __restrict__ W2, const float* __restrict__ al2,
                  const float* __restrict__ ar2,
                  __half* __restrict__ h2, float* __restrict__ el2, float* __restrict__ er2,
                  int nnodes)
{
    constexpr int H = 2, OUT = 64, OUT2 = 32;
    const int w = threadIdx.x >> 6, lane = threadIdx.x & 63;
    const int n = blockIdx.x * 4 + w;
    __shared__ int   sbuf[4][CAP + PAD];
    __shared__ float wbuf[4][H][CAP + PAD];
    __shared__ float orow[4][OUT];
    if (n >= nnodes) return;

    const int dn = min(deg[n], CAP);
    for (int i = lane; i < dn; i += 64) sbuf[w][i] = bucket[(long)n * CAP + i];
    if (lane < PAD) {
        sbuf[w][dn + lane]    = 0;
        wbuf[w][0][dn + lane] = 0.f;
        wbuf[w][1][dn + lane] = 0.f;
    }

    const int h = lane >> 5, li = lane & 31;
    const float ern = er[(long)n * H + h];
    float m = -INFINITY;
    for (int i = li; i < dn; i += 32) {
        float e = el[(long)sbuf[w][i] * H + h] + ern;
        e = (e > 0.f) ? e : 0.2f * e;
        wbuf[w][h][i] = e;
        m = fmaxf(m, e);
    }
    #pragma unroll
    for (int off = 16; off; off >>= 1) m = fmaxf(m, __shfl_xor(m, off, 64));
    float s = 0.f;
    for (int i = li; i < dn; i += 32) {
        float v = __expf(wbuf[w][h][i] - m);
        wbuf[w][h][i] = v;
        s += v;
    }
    #pragma unroll
    for (int off = 16; off; off >>= 1) s += __shfl_xor(s, off, 64);
    const float invh = (s > 0.f) ? 1.f / s : 0.f;
    const float inv0 = __shfl(invh, 0, 64);
    const float inv1 = __shfl(invh, 32, 64);

    const int q  = lane >> 3;
    const int c8 = lane & 7;
    const int hh = c8 >> 2;
    const float invC = hh ? inv1 : inv0;
    float acc[8] = {0.f,0.f,0.f,0.f,0.f,0.f,0.f,0.f};
    for (int i = 0; i < dn; i += 16) {
        const int   sA = sbuf[w][i + q],       sB = sbuf[w][i + 8 + q];
        const float wA = wbuf[w][hh][i + q],   wB = wbuf[w][hh][i + 8 + q];
        union { float4 f4; __half2 h2v[4]; } uA, uB;
        uA.f4 = *(const float4*)(hbuf + (long)sA * OUT + c8 * 8);
        uB.f4 = *(const float4*)(hbuf + (long)sB * OUT + c8 * 8);
        #pragma unroll
        for (int j = 0; j < 4; j++) {
            const float2 xa = __half22float2(uA.h2v[j]);
            const float2 xb = __half22float2(uB.h2v[j]);
            acc[2*j]   = fmaf(xa.x, wA, acc[2*j]);
            acc[2*j+1] = fmaf(xa.y, wA, acc[2*j+1]);
            acc[2*j]   = fmaf(xb.x, wB, acc[2*j]);
            acc[2*j+1] = fmaf(xb.y, wB, acc[2*j+1]);
        }
    }
    #pragma unroll
    for (int j = 0; j < 8; j++) {
        acc[j] += __shfl_xor(acc[j], 8, 64);
        acc[j] += __shfl_xor(acc[j], 16, 64);
        acc[j] += __shfl_xor(acc[j], 32, 64);
    }
    if (q == 0) {
        #pragma unroll
        for (int j = 0; j < 8; j++)
            orow[w][c8 * 8 + j] = fmaxf(acc[j] * invC + b1[c8 * 8 + j], 0.f);
    }

    const int p = lane >> 5, j2 = lane & 31;
    float g = 0.f;
    #pragma unroll
    for (int k = 0; k < 32; k++)
        g = fmaf(orow[w][p * 32 + k], W2[(p * 32 + k) * OUT2 + j2], g);
    g += __shfl_xor(g, 32, 64);

    float ev = g * al2[j2], rv = g * ar2[j2];
    #pragma unroll
    for (int off = 16; off; off >>= 1) { ev += __shfl_xor(ev, off, 64); rv += __shfl_xor(rv, off, 64); }
    if (lane < 32) h2[(long)n * OUT2 + j2] = __float2half(g);
    if (lane == 0) { el2[n] = ev; er2[n] = rv; }
}

// ---------------- agg layer2 (final output) ----------------
__global__ __launch_bounds__(256)
void k_agg2(const __half* __restrict__ h2, const float* __restrict__ el2,
            const float* __restrict__ er2, const int* __restrict__ deg,
            const int* __restrict__ bucket, const float* __restrict__ b2,
            float* __restrict__ out, int nnodes)
{
    constexpr int OUT2 = 32;
    const int w = threadIdx.x >> 6, lane = threadIdx.x & 63;
    const int n = blockIdx.x * 4 + w;
    __shared__ int   sbuf[4][CAP + PAD];
    __shared__ float wbuf[4][CAP + PAD];
    if (n >= nnodes) return;

    const int dn = min(deg[n], CAP);
    for (int i = lane; i < dn; i += 64) sbuf[w][i] = bucket[(long)n * CAP + i];
    if (lane < PAD) {
        sbuf[w][dn + lane] = 0;
        wbuf[w][dn + lane] = 0.f;
    }

    const float ern = er2[n];
    float m = -INFINITY;
    for (int i = lane; i < dn; i += 64) {
        float e = el2[sbuf[w][i]] + ern;
        e = (e > 0.f) ? e : 0.2f * e;
        wbuf[w][i] = e;
        m = fmaxf(m, e);
    }
    #pragma unroll
    for (int off = 32; off; off >>= 1) m = fmaxf(m, __shfl_xor(m, off, 64));
    float s = 0.f;
    for (int i = lane; i < dn; i += 64) {
        float v = __expf(wbuf[w][i] - m);
        wbuf[w][i] = v;
        s += v;
    }
    #pragma unroll
    for (int off = 32; off; off >>= 1) s += __shfl_xor(s, off, 64);
    const float inv = (s > 0.f) ? 1.f / s : 0.f;

    const int q  = lane >> 2;
    const int c8 = lane & 3;
    float acc[8] = {0.f,0.f,0.f,0.f,0.f,0.f,0.f,0.f};
    for (int i = 0; i < dn; i += 16) {
        const int   sA = sbuf[w][i + q];
        const float wA = wbuf[w][i + q];
        union { float4 f4; __half2 h2v[4]; } uA;
        uA.f4 = *(const float4*)(h2 + (long)sA * OUT2 + c8 * 8);
        #pragma unroll
        for (int j = 0; j < 4; j++) {
            const float2 xa = __half22float2(uA.h2v[j]);
            acc[2*j]   = fmaf(xa.x, wA, acc[2*j]);
            acc[2*j+1] = fmaf(xa.y, wA, acc[2*j+1]);
        }
    }
    #pragma unroll
    for (int j = 0; j < 8; j++) {
        acc[j] += __shfl_xor(acc[j], 4, 64);
        acc[j] += __shfl_xor(acc[j], 8, 64);
        acc[j] += __shfl_xor(acc[j], 16, 64);
        acc[j] += __shfl_xor(acc[j], 32, 64);
    }
    if (q == 0) {
        float r[8];
        #pragma unroll
        for (int j = 0; j < 8; j++)
            r[j] = fmaxf(acc[j] * inv + b2[c8 * 8 + j], 0.f);
        float4* po = (float4*)(out + (long)n * OUT2 + c8 * 8);
        po[0] = make_float4(r[0], r[1], r[2], r[3]);
        po[1] = make_float4(r[4], r[5], r[6], r[7]);
    }
}

extern "C" void kernel_launch(void* const* d_in, const int* in_sizes, int n_in,
                              void* d_out, int out_size, void* d_ws, size_t ws_size,
                              hipStream_t stream)
{
    const float* feat = (const float*)d_in[0];
    const float* W1   = (const float*)d_in[1];
    const float* al1  = (const float*)d_in[2];
    const float* ar1  = (const float*)d_in[3];
    const float* b1   = (const float*)d_in[4];
    const float* W2   = (const float*)d_in[5];
    const float* al2  = (const float*)d_in[6];
    const float* ar2  = (const float*)d_in[7];
    const float* b2   = (const float*)d_in[8];
    const int*   src  = (const int*)d_in[9];
    const int*   dst  = (const int*)d_in[10];

    const int N = in_sizes[0] / 128;   // 100000
    const int E = in_sizes[9];         // 1.7M
    const int NB = (N + 511) >> 9;     // 196 bins

    char* ws = (char*)d_ws;
    size_t off = 0;
    auto alloc = [&](size_t bytes) -> void* {
        void* p = ws + off;
        off += (bytes + 255) & ~size_t(255);
        return p;
    };
    int*      gcur   = (int*)     alloc((size_t)MAXB * 4);
    unsigned* binbuf = (unsigned*)alloc((size_t)NB * BCAP * 4);
    int*      deg    = (int*)     alloc((size_t)N * 4);
    int*      bucket = (int*)     alloc((size_t)N * CAP * 4);
    __half*   h1     = (__half*)  alloc((size_t)N * 64 * 2);
    float*    el1    = (float*)   alloc((size_t)N * 2 * 4);
    float*    er1    = (float*)   alloc((size_t)N * 2 * 4);
    __half*   h2     = (__half*)  alloc((size_t)N * 32 * 2);
    float*    el2    = (float*)   alloc((size_t)N * 4);
    float*    er2    = (float*)   alloc((size_t)N * 4);
    float*    vpre   = (float*)   alloc(512 * 4);

    hipMemsetAsync(gcur, 0, (size_t)NB * 4, stream);

    k_prew<<<1, 256, 0, stream>>>(W1, al1, ar1, vpre);
    k_bin<<<(E + TILE - 1) / TILE, 256, 0, stream>>>(src, dst, gcur, binbuf, E, NB);
    k_scatter<<<NB, 256, (512 + 512 * CAP) * 4, stream>>>(binbuf, gcur, deg, bucket, N);
    k_gemm1<<<(N + 63) / 64, 256, 0, stream>>>(feat, W1, h1, N);
    k_att1<<<(N * 16 + 255) / 256, 256, 0, stream>>>(feat, vpre, el1, er1, N);
    k_agg1_gemm2<<<(N + 3) / 4, 256, 0, stream>>>(h1, el1, er1, deg, bucket, b1,
                                                  W2, al2, ar2, h2, el2, er2, N);
    k_agg2<<<(N + 3) / 4, 256, 0, stream>>>(h2, el2, er2, deg, bucket, b2,
                                            (float*)d_out, N);
}

// Round 8
// 281.747 us; speedup vs baseline: 1.3473x; 1.0978x over previous
//
#include <hip/hip_runtime.h>
#include <hip/hip_fp16.h>
#include <math.h>

// GAT 2-layer forward, MI355X.
// k_prew -> k_front[bin || mfma-gemm1+att1] -> k_scatter -> k_agg1 -> k_gemm2(+att2) -> k_agg2
// Single-pass softmax (no max: logits O(5), shift-invariant), fp16 h tables,
// binned two-phase bucket build, MFMA for both GEMMs with fused logit columns.

constexpr int CAP  = 64;    // max in-degree (Poisson(16)+1, P(>=63)~4e-19)
constexpr int MAXB = 512;   // bin counter array size
constexpr int TILE = 2048;  // edges per bin block
constexpr int BCAP = 5120;  // records per 256-node bin (mean 4352, ~11 sigma)

typedef _Float16 f16x8 __attribute__((ext_vector_type(8)));
typedef float    f32x4 __attribute__((ext_vector_type(4)));

// ---- precompute: vh1[128][16] (att1 B-cols), B2h[64][64] (W2 | v2l | v2r | 0), zero gcur ----
__global__ __launch_bounds__(256)
void k_prew(const float* __restrict__ W1, const float* __restrict__ al1, const float* __restrict__ ar1,
            const float* __restrict__ W2, const float* __restrict__ al2, const float* __restrict__ ar2,
            _Float16* __restrict__ vh1, _Float16* __restrict__ B2h, int* __restrict__ gcur)
{
    const int t = threadIdx.x;
    for (int i = t; i < 128 * 16; i += 256) {       // cols: 0=el.h0 1=el.h1 2=er.h0 3=er.h1
        const int k = i >> 4, c = i & 15;
        float s = 0.f;
        if (c < 4) {
            const int h = c & 1;
            const float* a = (c >> 1) ? ar1 : al1;
            #pragma unroll
            for (int d = 0; d < 32; d++) s += W1[k * 64 + h * 32 + d] * a[h * 32 + d];
        }
        vh1[i] = (_Float16)s;
    }
    for (int i = t; i < 64 * 64; i += 256) {        // cols 0..31 = W2, 32 = W2·al2, 33 = W2·ar2
        const int k = i >> 6, c = i & 63;
        float s = 0.f;
        if (c < 32) s = W2[k * 32 + c];
        else if (c < 34) {
            const float* a = (c == 32) ? al2 : ar2;
            #pragma unroll
            for (int d = 0; d < 32; d++) s += W2[k * 32 + d] * a[d];
        }
        B2h[i] = (_Float16)s;
    }
    for (int b = t; b < MAXB; b += 256) gcur[b] = 0;   // FIX: cover all MAXB counters
}

// ---- fused front: edge binning blocks + MFMA gemm1(+att1 logit cols) blocks ----
__global__ __launch_bounds__(256)
void k_front(const int* __restrict__ src, const int* __restrict__ dst,
             int* __restrict__ gcur, unsigned* __restrict__ binbuf, int E, int Gbin,
             const float* __restrict__ x, const float* __restrict__ W,
             const _Float16* __restrict__ vh1,
             __half* __restrict__ h1, float* __restrict__ el, float* __restrict__ er,
             int nnodes)
{
    __shared__ alignas(16) char smem[32 * 1024];
    const int tid = threadIdx.x;

    if ((int)blockIdx.x < Gbin) {
        // ---- bin role: 2048 edges -> packed records (src<<8 | dst&255) per 256-node bin ----
        int* cnt  = (int*)smem;
        int* base = cnt + MAXB;
        for (int b = tid; b < MAXB; b += 256) cnt[b] = 0;
        __syncthreads();
        const int e0 = blockIdx.x * TILE;
        int lo[8]; unsigned rec[8]; int bn[8];
        #pragma unroll
        for (int u = 0; u < 8; u++) {
            const int e = e0 + u * 256 + tid;
            if (e < E) {
                const int d = dst[e];
                bn[u]  = d >> 8;
                rec[u] = ((unsigned)src[e] << 8) | (unsigned)(d & 255);
                lo[u]  = atomicAdd(&cnt[bn[u]], 1);
            } else bn[u] = -1;
        }
        __syncthreads();
        for (int b = tid; b < MAXB; b += 256) {
            const int c = cnt[b];
            base[b] = c ? atomicAdd(&gcur[b], c) : 0;
        }
        __syncthreads();
        #pragma unroll
        for (int u = 0; u < 8; u++) if (bn[u] >= 0) {
            const int p = base[bn[u]] + lo[u];
            if ((unsigned)p < (unsigned)BCAP)          // guards negative p too
                binbuf[(long)bn[u] * BCAP + p] = rec[u];
        }
        return;
    }

    // ---- gemm role: 64 nodes, x(fp32->fp16 swizzled LDS) @ W1 via MFMA 16x16x32 ----
    _Float16* xs = (_Float16*)smem;            // 64 x 128, XOR-swizzled
    _Float16* Wh = xs + 64 * 128;              // 128 x 64
    const int node0 = ((int)blockIdx.x - Gbin) * 64;

    for (int c = tid; c < 1024; c += 256) {
        const int row = c >> 4, k8 = c & 15;
        const int n = node0 + row;
        float4 v0 = make_float4(0, 0, 0, 0), v1 = v0;
        if (n < nnodes) {
            v0 = ((const float4*)x)[(long)n * 32 + k8 * 2];
            v1 = ((const float4*)x)[(long)n * 32 + k8 * 2 + 1];
        }
        f16x8 h;
        h[0] = v0.x; h[1] = v0.y; h[2] = v0.z; h[3] = v0.w;
        h[4] = v1.x; h[5] = v1.y; h[6] = v1.z; h[7] = v1.w;
        const int off = (row * 256 + k8 * 16) ^ ((row & 7) << 4);
        *(f16x8*)((char*)xs + off) = h;
    }
    for (int c = tid; c < 1024; c += 256) {
        const int k = c >> 3, j8 = (c & 7) * 8;
        float4 v0 = ((const float4*)W)[(k * 64 + j8) >> 2];
        float4 v1 = ((const float4*)W)[((k * 64 + j8) >> 2) + 1];
        f16x8 h;
        h[0] = v0.x; h[1] = v0.y; h[2] = v0.z; h[3] = v0.w;
        h[4] = v1.x; h[5] = v1.y; h[6] = v1.z; h[7] = v1.w;
        *(f16x8*)(Wh + k * 64 + j8) = h;
    }
    __syncthreads();

    const int wv = tid >> 6, l = tid & 63;
    const int col = wv * 16 + (l & 15);
    const int g = l >> 4;
    f16x8 bfr[4], vfr[4];
    #pragma unroll
    for (int t = 0; t < 4; t++)
        #pragma unroll
        for (int e = 0; e < 8; e++)
            bfr[t][e] = Wh[(t * 32 + g * 8 + e) * 64 + col];
    if (wv == 0) {
        #pragma unroll
        for (int t = 0; t < 4; t++)
            #pragma unroll
            for (int e = 0; e < 8; e++)
                vfr[t][e] = vh1[(t * 32 + g * 8 + e) * 16 + (l & 15)];
    }

    #pragma unroll
    for (int nt = 0; nt < 4; nt++) {
        f32x4 acc = {0.f, 0.f, 0.f, 0.f}, accv = {0.f, 0.f, 0.f, 0.f};
        const int row = nt * 16 + (l & 15);
        #pragma unroll
        for (int t = 0; t < 4; t++) {
            const int off = (row * 256 + (t * 32 + g * 8) * 2) ^ ((row & 7) << 4);
            f16x8 af = *(const f16x8*)((const char*)xs + off);
            acc = __builtin_amdgcn_mfma_f32_16x16x32_f16(af, bfr[t], acc, 0, 0, 0);
            if (wv == 0)
                accv = __builtin_amdgcn_mfma_f32_16x16x32_f16(af, vfr[t], accv, 0, 0, 0);
        }
        #pragma unroll
        for (int r = 0; r < 4; r++) {
            const int n = node0 + nt * 16 + g * 4 + r;
            if (n < nnodes) {
                h1[(long)n * 64 + col] = __float2half((float)acc[r]);
                if (wv == 0) {
                    const int c4 = l & 15;
                    if (c4 < 2)      el[n * 2 + c4]       = (float)accv[r];
                    else if (c4 < 4) er[n * 2 + (c4 - 2)] = (float)accv[r];
                }
            }
        }
    }
}

// ---- phase 2: per-256-node-bin LDS bucket window, dense write-out ----
__global__ __launch_bounds__(256)
void k_scatter(const unsigned* __restrict__ binbuf, const int* __restrict__ gcur,
               int* __restrict__ deg, int* __restrict__ bucket, int nnodes)
{
    extern __shared__ int lds[];          // ldeg[256] + lbuck[256*CAP]
    int* ldeg  = lds;
    int* lbuck = lds + 256;
    const int t = threadIdx.x, b = blockIdx.x;
    const int nb0 = b << 8;
    ldeg[t] = 0;
    __syncthreads();
    const int cnt = min(max(gcur[b], 0), BCAP);
    const unsigned* recs = binbuf + (long)b * BCAP;
    for (int i = t; i < cnt; i += 256) {
        const unsigned r = recs[i];
        const int nl  = (int)(r & 255u);
        const int pos = atomicAdd(&ldeg[nl], 1);
        if (pos < CAP) lbuck[nl * CAP + pos] = (int)(r >> 8);
    }
    __syncthreads();
    const int nv = min(256, nnodes - nb0);
    if (t < nv) deg[nb0 + t] = ldeg[t];
    const int tot4 = nv * (CAP / 4);
    int4* gb = (int4*)(bucket + (long)nb0 * CAP);
    const int4* lb = (const int4*)lbuck;
    for (int i = t; i < tot4; i += 256) gb[i] = lb[i];
}

// ---- agg layer1: single-pass unnormalized softmax + 16B-gather; o1 out fp16 ----
__global__ __launch_bounds__(256)
void k_agg1(const __half* __restrict__ hbuf, const float* __restrict__ el,
            const float* __restrict__ er, const int* __restrict__ deg,
            const int* __restrict__ bucket, const float* __restrict__ b1,
            __half* __restrict__ o1, int nnodes)
{
    constexpr int OUT = 64;
    const int w = threadIdx.x >> 6, lane = threadIdx.x & 63;
    const int n = blockIdx.x * 4 + w;
    __shared__ int    sbuf[4][CAP];
    __shared__ float2 wbuf[4][CAP];
    if (n >= nnodes) return;                     // wave-uniform; no barriers below

    const int dn = min(deg[n], CAP);
    const int sv = (lane < dn) ? bucket[(long)n * CAP + lane] : 0;
    sbuf[w][lane] = sv;

    // weights for all <=64 edges in one parallel step (softmax shift-invariant, |e|<~6)
    const float2 ernv = ((const float2*)er)[n];
    const float2 elv  = ((const float2*)el)[sv];
    float e0 = elv.x + ernv.x; e0 = (e0 > 0.f) ? e0 : 0.2f * e0;
    float e1 = elv.y + ernv.y; e1 = (e1 > 0.f) ? e1 : 0.2f * e1;
    const float w0 = (lane < dn) ? __expf(e0) : 0.f;
    const float w1 = (lane < dn) ? __expf(e1) : 0.f;
    wbuf[w][lane] = make_float2(w0, w1);
    float s0 = w0, s1 = w1;
    #pragma unroll
    for (int off = 32; off; off >>= 1) {
        s0 += __shfl_xor(s0, off, 64);
        s1 += __shfl_xor(s1, off, 64);
    }
    const float inv0 = (s0 > 0.f) ? 1.f / s0 : 0.f;
    const float inv1 = (s1 > 0.f) ? 1.f / s1 : 0.f;

    // gather: 8 lanes/row (16B fp16 each), 16 edge slots/iter
    const int q = lane >> 3, c8 = lane & 7, hh = c8 >> 2;
    const float invC = hh ? inv1 : inv0;
    float acc[8] = {0.f,0.f,0.f,0.f,0.f,0.f,0.f,0.f};
    for (int i = 0; i < dn; i += 16) {
        const int   sA = sbuf[w][i + q],                     sB = sbuf[w][i + 8 + q];
        const float wA = ((const float*)&wbuf[w][i + q])[hh];
        const float wB = ((const float*)&wbuf[w][i + 8 + q])[hh];
        union { float4 f4; __half2 h2v[4]; } uA, uB;
        uA.f4 = *(const float4*)(hbuf + (long)sA * OUT + c8 * 8);
        uB.f4 = *(const float4*)(hbuf + (long)sB * OUT + c8 * 8);
        #pragma unroll
        for (int j = 0; j < 4; j++) {
            const float2 xa = __half22float2(uA.h2v[j]);
            const float2 xb = __half22float2(uB.h2v[j]);
            acc[2*j]   = fmaf(xa.x, wA, acc[2*j]);
            acc[2*j+1] = fmaf(xa.y, wA, acc[2*j+1]);
            acc[2*j]   = fmaf(xb.x, wB, acc[2*j]);
            acc[2*j+1] = fmaf(xb.y, wB, acc[2*j+1]);
        }
    }
    #pragma unroll
    for (int j = 0; j < 8; j++) {
        acc[j] += __shfl_xor(acc[j], 8, 64);
        acc[j] += __shfl_xor(acc[j], 16, 64);
        acc[j] += __shfl_xor(acc[j], 32, 64);
    }
    if (q == 0) {
        f16x8 ov;
        #pragma unroll
        for (int j = 0; j < 8; j++)
            ov[j] = (_Float16)fmaxf(acc[j] * invC + b1[c8 * 8 + j], 0.f);
        *(f16x8*)((char*)o1 + (long)n * 128 + c8 * 16) = ov;
    }
}

// ---- gemm2 via MFMA: h2 = o1 @ W2 (fp16), el2/er2 from B-cols 32/33 ----
__global__ __launch_bounds__(256)
void k_gemm2(const __half* __restrict__ o1, const _Float16* __restrict__ B2h,
             __half* __restrict__ h2, float* __restrict__ el2, float* __restrict__ er2,
             int nnodes)
{
    __shared__ _Float16 xs[64 * 64];     // 64 rows x 64 k, XOR-swizzled (128B rows)
    const int tid = threadIdx.x;
    const int node0 = blockIdx.x * 64;

    for (int c = tid; c < 512; c += 256) {
        const int row = c >> 3, k8 = c & 7;
        const int n = node0 + row;
        f16x8 h = {0,0,0,0,0,0,0,0};
        if (n < nnodes) h = *(const f16x8*)((const char*)o1 + (long)n * 128 + k8 * 16);
        const int off = (row * 128 + k8 * 16) ^ ((row & 7) << 4);
        *(f16x8*)((char*)xs + off) = h;
    }
    __syncthreads();

    const int wv = tid >> 6, l = tid & 63;
    if (wv == 3) return;                         // cols 48..63 are zero padding
    const int col = wv * 16 + (l & 15);
    const int g = l >> 4;
    f16x8 bfr[2];
    #pragma unroll
    for (int t = 0; t < 2; t++)
        #pragma unroll
        for (int e = 0; e < 8; e++)
            bfr[t][e] = B2h[(t * 32 + g * 8 + e) * 64 + col];

    #pragma unroll
    for (int nt = 0; nt < 4; nt++) {
        f32x4 acc = {0.f, 0.f, 0.f, 0.f};
        const int row = nt * 16 + (l & 15);
        #pragma unroll
        for (int t = 0; t < 2; t++) {
            const int off = (row * 128 + (t * 32 + g * 8) * 2) ^ ((row & 7) << 4);
            f16x8 af = *(const f16x8*)((const char*)xs + off);
            acc = __builtin_amdgcn_mfma_f32_16x16x32_f16(af, bfr[t], acc, 0, 0, 0);
        }
        #pragma unroll
        for (int r = 0; r < 4; r++) {
            const int n = node0 + nt * 16 + g * 4 + r;
            if (n < nnodes) {
                if (wv < 2) h2[(long)n * 32 + col] = __float2half((float)acc[r]);
                else {
                    const int c4 = l & 15;
                    if (c4 == 0)      el2[n] = (float)acc[r];
                    else if (c4 == 1) er2[n] = (float)acc[r];
                }
            }
        }
    }
}

// ---- agg layer2 (final output, fp32) ----
__global__ __launch_bounds__(256)
void k_agg2(const __half* __restrict__ h2, const float* __restrict__ el2,
            const float* __restrict__ er2, const int* __restrict__ deg,
            const int* __restrict__ bucket, const float* __restrict__ b2,
            float* __restrict__ out, int nnodes)
{
    const int w = threadIdx.x >> 6, lane = threadIdx.x & 63;
    const int n = blockIdx.x * 4 + w;
    __shared__ int   sbuf[4][CAP];
    __shared__ float wbuf[4][CAP];
    if (n >= nnodes) return;

    const int dn = min(deg[n], CAP);
    const int sv = (lane < dn) ? bucket[(long)n * CAP + lane] : 0;
    sbuf[w][lane] = sv;

    const float ern = er2[n];
    float e = el2[sv] + ern; e = (e > 0.f) ? e : 0.2f * e;
    const float wt = (lane < dn) ? __expf(e) : 0.f;
    wbuf[w][lane] = wt;
    float s = wt;
    #pragma unroll
    for (int off = 32; off; off >>= 1) s += __shfl_xor(s, off, 64);
    const float inv = (s > 0.f) ? 1.f / s : 0.f;

    // gather: 4 lanes/row (16B fp16 each), 16 edge slots/iter
    const int q = lane >> 2, c8 = lane & 3;
    float acc[8] = {0.f,0.f,0.f,0.f,0.f,0.f,0.f,0.f};
    for (int i = 0; i < dn; i += 16) {
        const int   sA = sbuf[w][i + q];
        const float wA = wbuf[w][i + q];
        union { float4 f4; __half2 h2v[4]; } uA;
        uA.f4 = *(const float4*)(h2 + (long)sA * 32 + c8 * 8);
        #pragma unroll
        for (int j = 0; j < 4; j++) {
            const float2 xa = __half22float2(uA.h2v[j]);
            acc[2*j]   = fmaf(xa.x, wA, acc[2*j]);
            acc[2*j+1] = fmaf(xa.y, wA, acc[2*j+1]);
        }
    }
    #pragma unroll
    for (int j = 0; j < 8; j++) {
        acc[j] += __shfl_xor(acc[j], 4, 64);
        acc[j] += __shfl_xor(acc[j], 8, 64);
        acc[j] += __shfl_xor(acc[j], 16, 64);
        acc[j] += __shfl_xor(acc[j], 32, 64);
    }
    if (q == 0) {
        float r[8];
        #pragma unroll
        for (int j = 0; j < 8; j++)
            r[j] = fmaxf(acc[j] * inv + b2[c8 * 8 + j], 0.f);
        float4* po = (float4*)(out + (long)n * 32 + c8 * 8);
        po[0] = make_float4(r[0], r[1], r[2], r[3]);
        po[1] = make_float4(r[4], r[5], r[6], r[7]);
    }
}

extern "C" void kernel_launch(void* const* d_in, const int* in_sizes, int n_in,
                              void* d_out, int out_size, void* d_ws, size_t ws_size,
                              hipStream_t stream)
{
    const float* feat = (const float*)d_in[0];
    const float* W1   = (const float*)d_in[1];
    const float* al1  = (const float*)d_in[2];
    const float* ar1  = (const float*)d_in[3];
    const float* b1   = (const float*)d_in[4];
    const float* W2   = (const float*)d_in[5];
    const float* al2  = (const float*)d_in[6];
    const float* ar2  = (const float*)d_in[7];
    const float* b2   = (const float*)d_in[8];
    const int*   src  = (const int*)d_in[9];
    const int*   dst  = (const int*)d_in[10];

    const int N  = in_sizes[0] / 128;   // 100000
    const int E  = in_sizes[9];         // 1.7M
    const int NB = (N + 255) >> 8;      // 391 bins

    char* ws = (char*)d_ws;
    size_t off = 0;
    auto alloc = [&](size_t bytes) -> void* {
        void* p = ws + off;
        off += (bytes + 255) & ~size_t(255);
        return p;
    };
    // region A: binbuf (live front..scatter) aliased with o1 (live agg1..gemm2)
    const size_t szA = ((size_t)NB * BCAP * 4 > (size_t)N * 64 * 2)
                     ? (size_t)NB * BCAP * 4 : (size_t)N * 64 * 2;
    char*     A      = (char*)    alloc(szA);
    unsigned* binbuf = (unsigned*)A;
    __half*   o1     = (__half*)  A;
    // region B: h1 (live front..agg1) aliased with h2 (live gemm2..agg2)
    char*     B      = (char*)    alloc((size_t)N * 64 * 2);
    __half*   h1     = (__half*)  B;
    __half*   h2     = (__half*)  B;
    int*      gcur   = (int*)     alloc((size_t)MAXB * 4);
    int*      deg    = (int*)     alloc((size_t)N * 4);
    int*      bucket = (int*)     alloc((size_t)N * CAP * 4);
    float*    el1    = (float*)   alloc((size_t)N * 2 * 4);
    float*    er1    = (float*)   alloc((size_t)N * 2 * 4);
    float*    el2    = (float*)   alloc((size_t)N * 4);
    float*    er2    = (float*)   alloc((size_t)N * 4);
    _Float16* vh1    = (_Float16*)alloc(128 * 16 * 2);
    _Float16* B2h    = (_Float16*)alloc(64 * 64 * 2);

    const int Gbin  = (E + TILE - 1) / TILE;     // 830
    const int Ggemm = (N + 63) / 64;             // 1563

    k_prew<<<1, 256, 0, stream>>>(W1, al1, ar1, W2, al2, ar2, vh1, B2h, gcur);
    k_front<<<Gbin + Ggemm, 256, 0, stream>>>(src, dst, gcur, binbuf, E, Gbin,
                                              feat, W1, vh1, h1, el1, er1, N);
    k_scatter<<<NB, 256, (256 + 256 * CAP) * 4, stream>>>(binbuf, gcur, deg, bucket, N);
    k_agg1<<<(N + 3) / 4, 256, 0, stream>>>(h1, el1, er1, deg, bucket, b1, o1, N);
    k_gemm2<<<(N + 63) / 64, 256, 0, stream>>>(o1, B2h, h2, el2, er2, N);
    k_agg2<<<(N + 3) / 4, 256, 0, stream>>>(h2, el2, er2, deg, bucket, b2,
                                            (float*)d_out, N);
}